// Round 1
// baseline (970.666 us; speedup 1.0000x reference)
//
#include <hip/hip_runtime.h>

// Problem constants
#define N_    8
#define CH_   512
#define SD_   512
#define CIG_  8
#define NG_   64
#define H_    128
#define W_    128
#define HW_   16384
#define KDW   2048        // 512 ci * 4 (2x2 window)
#define NP_   72          // 8 n * 9 kernel positions
#define OC_   4096        // CH_*CIG_

// Workspace layout (floats). Total 786432 floats = 3.0 MB.
#define WS_B     0
#define WS_SPOOL (WS_B + NP_ * KDW)          // 147456
#define WS_PWKN  (WS_SPOOL + N_ * SD_)       // 151552
#define WS_PWB   (WS_PWKN + N_ * OC_)        // 184320
#define WS_DW    (WS_PWB + N_ * CH_)         // 188416
#define WS_E     (WS_DW + N_ * OC_ * 9)      // 483328
#define WS_MEAN  (WS_E + N_ * OC_ * 9)       // 778240
#define WS_RSTD  (WS_MEAN + N_ * CH_)        // 782336

// ---------------------------------------------------------------------------
// prep: im2col of style (B[np][k]), style avg-pool (spool), zero dw accum
// ---------------------------------------------------------------------------
__global__ __launch_bounds__(256) void prep(const float* __restrict__ style,
                                            float* __restrict__ B,
                                            float* __restrict__ spool,
                                            float* __restrict__ dwacc) {
  const int idx = blockIdx.x * 256 + threadIdx.x;
  const int NB = NP_ * KDW;        // 147456
  const int NS = N_ * SD_;         // 4096
  const int NZ = N_ * OC_ * 9;     // 294912
  if (idx < NB) {
    const int np = idx >> 11;
    const int k = idx & 2047;
    const int n = np / 9, p = np % 9;
    const int py = p / 3, px = p % 3;
    const int ci = k >> 2, uv = k & 3;
    const int u = uv >> 1, v = uv & 1;
    B[idx] = style[(n * SD_ + ci) * 16 + (py + u) * 4 + (px + v)];
  } else if (idx < NB + NS) {
    const int j = idx - NB;
    const float* s = style + j * 16;
    float a = 0.f;
#pragma unroll
    for (int t = 0; t < 16; t++) a += s[t];
    spool[j] = a * (1.0f / 16.0f);
  } else if (idx < NB + NS + NZ) {
    dwacc[idx - NB - NS] = 0.0f;
  }
}

// ---------------------------------------------------------------------------
// stats: per-(n,c) mean and 1/sqrt(var_unbiased + 1e-5) over 128x128
// ---------------------------------------------------------------------------
__global__ __launch_bounds__(256) void stats(const float* __restrict__ pred,
                                             float* __restrict__ meanv,
                                             float* __restrict__ rstdv) {
  const int nc = blockIdx.x;  // 0..4095
  const float4* p = (const float4*)(pred + (size_t)nc * HW_);
  float s = 0.f, s2 = 0.f;
#pragma unroll
  for (int i = 0; i < 16; i++) {
    const float4 v = p[threadIdx.x + 256 * i];
    s += v.x + v.y + v.z + v.w;
    s2 += v.x * v.x + v.y * v.y + v.z * v.z + v.w * v.w;
  }
  for (int off = 32; off > 0; off >>= 1) {
    s += __shfl_down(s, off, 64);
    s2 += __shfl_down(s2, off, 64);
  }
  __shared__ float as[4], as2[4];
  const int wv = threadIdx.x >> 6;
  if ((threadIdx.x & 63) == 0) { as[wv] = s; as2[wv] = s2; }
  __syncthreads();
  if (threadIdx.x == 0) {
    const float S = as[0] + as[1] + as[2] + as[3];
    const float S2 = as2[0] + as2[1] + as2[2] + as2[3];
    const float mean = S * (1.0f / HW_);
    const float var = (S2 - S * mean) * (1.0f / (HW_ - 1));
    meanv[nc] = mean;
    rstdv[nc] = 1.0f / sqrtf(var + 1e-5f);
  }
}

// ---------------------------------------------------------------------------
// pw_gemm: pw_kn (8x4096) and pw_bias (8x512); K=512, one column per thread
// ---------------------------------------------------------------------------
__global__ __launch_bounds__(256) void pw_gemm(const float* __restrict__ spool,
                                               const float* __restrict__ pkw,
                                               const float* __restrict__ pkb,
                                               const float* __restrict__ pbw,
                                               const float* __restrict__ pbb,
                                               float* __restrict__ pwkn,
                                               float* __restrict__ pwbias) {
  __shared__ float sp[N_ * SD_];
  for (int i = threadIdx.x; i < N_ * SD_; i += 256) sp[i] = spool[i];
  __syncthreads();
  const int col = blockIdx.x * 256 + threadIdx.x;  // 0..4607
  const float* w;
  float bias;
  if (col < OC_) { w = pkw + (size_t)col * SD_; bias = pkb[col]; }
  else           { w = pbw + (size_t)(col - OC_) * SD_; bias = pbb[col - OC_]; }
  float acc[8];
#pragma unroll
  for (int nn = 0; nn < 8; nn++) acc[nn] = 0.f;
  for (int k = 0; k < SD_; k += 4) {
    const float4 wv = *(const float4*)(w + k);
#pragma unroll
    for (int nn = 0; nn < 8; nn++) {
      const float4 sv = *(const float4*)(&sp[nn * SD_ + k]);
      acc[nn] = fmaf(wv.x, sv.x, acc[nn]);
      acc[nn] = fmaf(wv.y, sv.y, acc[nn]);
      acc[nn] = fmaf(wv.z, sv.z, acc[nn]);
      acc[nn] = fmaf(wv.w, sv.w, acc[nn]);
    }
  }
  if (col < OC_) {
#pragma unroll
    for (int nn = 0; nn < 8; nn++) pwkn[nn * OC_ + col] = acc[nn] + bias;
  } else {
#pragma unroll
    for (int nn = 0; nn < 8; nn++) pwbias[nn * CH_ + (col - OC_)] = acc[nn] + bias;
  }
}

// ---------------------------------------------------------------------------
// dw_gemm: dw[np=72][co=4096], K=2048. Grid (32 co-tiles, 8 K-splits).
// W (dw_w) transposed into LDS [k][co] (stride 129 -> conflict-free b32 reads).
// B read via wave-uniform scalar loads (readfirstlane forces SGPR path).
// Partial sums accumulated with fp32 atomics into zeroed dwacc.
// ---------------------------------------------------------------------------
__global__ __launch_bounds__(256) void dw_gemm(const float* __restrict__ Bg,
                                               const float* __restrict__ Wg,
                                               float* __restrict__ dwacc) {
  __shared__ float Wl[64 * 129];
  const int t = threadIdx.x;
  const int co0 = blockIdx.x * 128;
  const int kbase = blockIdx.y * 256;
  const int co = t & 127;
  const int npb = __builtin_amdgcn_readfirstlane((t >> 7) * 36);
  float acc[36];
#pragma unroll
  for (int j = 0; j < 36; j++) acc[j] = 0.f;

  for (int kc = 0; kc < 256; kc += 64) {
    __syncthreads();
    {
      const int kq = (t & 15) * 4;
      const int cob = t >> 4;
#pragma unroll
      for (int r = 0; r < 8; r++) {
        const int c = cob + r * 16;
        const float4 wv =
            *(const float4*)(Wg + (size_t)(co0 + c) * KDW + kbase + kc + kq);
        Wl[(kq + 0) * 129 + c] = wv.x;
        Wl[(kq + 1) * 129 + c] = wv.y;
        Wl[(kq + 2) * 129 + c] = wv.z;
        Wl[(kq + 3) * 129 + c] = wv.w;
      }
    }
    __syncthreads();
    const float* Bp = Bg + kbase + kc;
    for (int k = 0; k < 64; k += 4) {
      const float w0 = Wl[(k + 0) * 129 + co];
      const float w1 = Wl[(k + 1) * 129 + co];
      const float w2 = Wl[(k + 2) * 129 + co];
      const float w3 = Wl[(k + 3) * 129 + co];
#pragma unroll
      for (int j = 0; j < 36; j++) {
        const float4 b = *(const float4*)(Bp + (npb + j) * KDW + k);
        float a = acc[j];
        a = fmaf(w0, b.x, a);
        a = fmaf(w1, b.y, a);
        a = fmaf(w2, b.z, a);
        a = fmaf(w3, b.w, a);
        acc[j] = a;
      }
    }
  }
#pragma unroll
  for (int j = 0; j < 36; j++) {
    const int np = npb + j;
    const int n = np / 9, p = np % 9;
    atomicAdd(dwacc + (size_t)(n * OC_ + co0 + co) * 9 + p, acc[j]);
  }
}

// ---------------------------------------------------------------------------
// eff_k: fold pointwise into depthwise: E[n][gc][ci][p][co] =
//        sum_j pw_kn[n][gc*8+co][j] * (dw[n][(gc*8+j)*8+ci][p] + dw_b[...])
// ---------------------------------------------------------------------------
__global__ __launch_bounds__(256) void eff_k(const float* __restrict__ dwacc,
                                             const float* __restrict__ dwb,
                                             const float* __restrict__ pwkn,
                                             float* __restrict__ Eg) {
  const int idx = blockIdx.x * 256 + threadIdx.x;  // < 294912
  const int co = idx & 7;
  int tmp = idx >> 3;
  const int p = tmp % 9;
  tmp /= 9;
  const int ci = tmp & 7;
  tmp >>= 3;
  const int gc = tmp & 63;
  const int n = tmp >> 6;
  const int c = gc * 8 + co;
  float a = 0.f;
#pragma unroll
  for (int j = 0; j < 8; j++) {
    const int ch = (gc * 8 + j) * 8 + ci;
    a = fmaf(pwkn[n * OC_ + c * 8 + j],
             dwacc[(size_t)(n * OC_ + ch) * 9 + p] + dwb[ch], a);
  }
  Eg[idx] = a;
}

// ---------------------------------------------------------------------------
// main_conv: instance-norm + reflect-pad + effective 8-in/8-out 3x3 conv
// Block: (ytile 16 rows, group gc, sample n). 256 threads, 8co x 8px per thread.
// ---------------------------------------------------------------------------
#define ROWS 16
__global__ __launch_bounds__(256) void main_conv(const float* __restrict__ pred,
                                                 const float* __restrict__ Eg,
                                                 const float* __restrict__ pwb,
                                                 const float* __restrict__ meanv,
                                                 const float* __restrict__ rstdv,
                                                 float* __restrict__ out) {
  __shared__ float xl[8 * 18 * 132];   // 76032 B
  __shared__ float El[8 * 9 * 8];      // [ci][p][co]
  __shared__ float cm[8], cr[8];
  const int t = threadIdx.x;
  const int yt = blockIdx.x;  // 0..7
  const int gc = blockIdx.y;  // 0..63
  const int n = blockIdx.z;   // 0..7
  const int chbase = n * CH_ + gc * 8;

  if (t < 8) {
    cm[t] = meanv[chbase + t];
    cr[t] = rstdv[chbase + t];
  }
  for (int i = t; i < 576; i += 256)
    El[i] = Eg[(size_t)(n * 64 + gc) * 576 + i];
  __syncthreads();

  const int y0 = yt * ROWS;
  for (int i = t; i < 8 * 18 * 130; i += 256) {
    const int col = i % 130;
    const int rr = (i / 130) % 18;
    const int ci = i / (130 * 18);
    int gy = y0 + rr - 1;
    gy = gy < 0 ? -gy : (gy > 127 ? 254 - gy : gy);
    int gx = col - 1;
    gx = gx < 0 ? -gx : (gx > 127 ? 254 - gx : gx);
    const float v = pred[((size_t)(chbase + ci) * 128 + gy) * 128 + gx];
    xl[(ci * 18 + rr) * 132 + col] = (v - cm[ci]) * cr[ci];
  }
  __syncthreads();

  const int y = t >> 4;          // 0..15
  const int xb = (t & 15) * 8;   // 0..120
  float acc[8][8];
#pragma unroll
  for (int co = 0; co < 8; co++)
#pragma unroll
    for (int px = 0; px < 8; px++) acc[co][px] = 0.f;

#pragma unroll 1
  for (int ci = 0; ci < 8; ci++) {
#pragma unroll
    for (int ky = 0; ky < 3; ky++) {
      const float* xr = &xl[(ci * 18 + y + ky) * 132 + xb];
      const float4 xa = *(const float4*)(xr);
      const float4 xc = *(const float4*)(xr + 4);
      const float xw[10] = {xa.x, xa.y, xa.z, xa.w, xc.x,
                            xc.y, xc.z, xc.w, xr[8], xr[9]};
#pragma unroll
      for (int kx = 0; kx < 3; kx++) {
        const float4 e0 = *(const float4*)(&El[(ci * 9 + ky * 3 + kx) * 8]);
        const float4 e1 = *(const float4*)(&El[(ci * 9 + ky * 3 + kx) * 8 + 4]);
        const float ev[8] = {e0.x, e0.y, e0.z, e0.w, e1.x, e1.y, e1.z, e1.w};
#pragma unroll
        for (int co = 0; co < 8; co++)
#pragma unroll
          for (int px = 0; px < 8; px++)
            acc[co][px] = fmaf(ev[co], xw[kx + px], acc[co][px]);
      }
    }
  }

  const int gy = y0 + y;
#pragma unroll
  for (int co = 0; co < 8; co++) {
    const float b = pwb[chbase + co];
    float* op = out + ((size_t)(chbase + co) * 128 + gy) * 128 + xb;
    float4 o0, o1;
    o0.x = acc[co][0] + b; o0.y = acc[co][1] + b;
    o0.z = acc[co][2] + b; o0.w = acc[co][3] + b;
    o1.x = acc[co][4] + b; o1.y = acc[co][5] + b;
    o1.z = acc[co][6] + b; o1.w = acc[co][7] + b;
    *(float4*)op = o0;
    *(float4*)(op + 4) = o1;
  }
}

// ---------------------------------------------------------------------------
extern "C" void kernel_launch(void* const* d_in, const int* in_sizes, int n_in,
                              void* d_out, int out_size, void* d_ws,
                              size_t ws_size, hipStream_t stream) {
  const float* style = (const float*)d_in[0];
  const float* pred = (const float*)d_in[1];
  const float* dww = (const float*)d_in[2];
  const float* dwb = (const float*)d_in[3];
  const float* pkw = (const float*)d_in[4];
  const float* pkb = (const float*)d_in[5];
  const float* pbw = (const float*)d_in[6];
  const float* pbb = (const float*)d_in[7];
  float* out = (float*)d_out;
  float* ws = (float*)d_ws;

  float* B = ws + WS_B;
  float* spool = ws + WS_SPOOL;
  float* pwkn = ws + WS_PWKN;
  float* pwbias = ws + WS_PWB;
  float* dwacc = ws + WS_DW;
  float* Eg = ws + WS_E;
  float* meanv = ws + WS_MEAN;
  float* rstdv = ws + WS_RSTD;

  prep<<<dim3(1744), dim3(256), 0, stream>>>(style, B, spool, dwacc);
  stats<<<dim3(4096), dim3(256), 0, stream>>>(pred, meanv, rstdv);
  pw_gemm<<<dim3(18), dim3(256), 0, stream>>>(spool, pkw, pkb, pbw, pbb, pwkn,
                                              pwbias);
  dw_gemm<<<dim3(32, 8), dim3(256), 0, stream>>>(B, dww, dwacc);
  eff_k<<<dim3(1152), dim3(256), 0, stream>>>(dwacc, dwb, pwkn, Eg);
  main_conv<<<dim3(8, 64, 8), dim3(256), 0, stream>>>(pred, Eg, pwbias, meanv,
                                                      rstdv, out);
}